// Round 17
// baseline (555.604 us; speedup 1.0000x reference)
//
#include <hip/hip_runtime.h>
#include <math.h>

#define B 8192
#define D 1024
#define INV_T (1.0f/0.07f)
#define CMAX (1.0f/0.07f)   // upper bound on any logit (unit-norm rows): fixed LSE max
#define SPLITS 8
#define CW (B/SPLITS)
#define MAXM 256            // max class size (mean 82)
#define NCLS 100
#define NRB (B/128)         // 64 row blocks
#define NTRI (NRB*(NRB+1)/2) // 2080 triangular tiles (2080 % 8 == 0)
#define NCONV (B*D/4/256)   // 8192 convert blocks

typedef __attribute__((ext_vector_type(4))) float  f32x4;
typedef __attribute__((ext_vector_type(8))) int    i32x8;

// swap bits 0 and 2 (involution on 0..7) -- chunk<->slot permutation
__device__ __forceinline__ int sw02(int x) {
    return (x & 2) | ((x & 1) << 2) | ((x >> 2) & 1);
}

// ---------------- fused: fp32->fp8 convert (blocks 0..8191) + per-class lists + rank ----------------
__global__ __launch_bounds__(256) void convert_classlist_kernel(const float* __restrict__ E,
                                                                unsigned char* __restrict__ E8,
                                                                const int* __restrict__ labels,
                                                                int* __restrict__ members,
                                                                int* __restrict__ cnt,
                                                                int* __restrict__ rank) {
    if (blockIdx.x < NCONV) {
        int i = blockIdx.x * 256 + threadIdx.x;          // covers B*D/4
        float4 v = ((const float4*)E)[i];
        int lo = __builtin_amdgcn_cvt_pk_fp8_f32(v.x, v.y, 0, false);   // bytes 0,1
        int pk = __builtin_amdgcn_cvt_pk_fp8_f32(v.z, v.w, lo, true);   // bytes 2,3
        ((int*)E8)[i] = pk;
        return;
    }
    const int c  = blockIdx.x - NCONV;
    const int tt = threadIdx.x;
    const int lane = tt & 63, w = tt >> 6;
    __shared__ int wcnt[4];
    int cw = 0;
    for (int b0 = w * 2048; b0 < (w + 1) * 2048; b0 += 256) {
        int4 lv = ((const int4*)labels)[(b0 >> 2) + lane];
        cw += __popcll(__ballot(lv.x == c)) + __popcll(__ballot(lv.y == c))
            + __popcll(__ballot(lv.z == c)) + __popcll(__ballot(lv.w == c));
    }
    if (lane == 0) wcnt[w] = cw;
    __syncthreads();
    int cum = 0;
    for (int x = 0; x < w; ++x) cum += wcnt[x];
    for (int b0 = w * 2048; b0 < (w + 1) * 2048; b0 += 256) {
        int4 lv = ((const int4*)labels)[(b0 >> 2) + lane];
        unsigned long long k0 = __ballot(lv.x == c), k1 = __ballot(lv.y == c);
        unsigned long long k2 = __ballot(lv.z == c), k3 = __ballot(lv.w == c);
        unsigned long long below = (1ull << lane) - 1ull;
        int prelane = __popcll(k0 & below) + __popcll(k1 & below)
                    + __popcll(k2 & below) + __popcll(k3 & below);
        int m0 = (lv.x == c), m1 = (lv.y == c), m2 = (lv.z == c), m3 = (lv.w == c);
        int basep = cum + prelane;
        int j0 = b0 + 4 * lane;
        if (m0) { members[c * MAXM + basep] = j0;                rank[j0]     = basep; }
        if (m1) { members[c * MAXM + basep + m0] = j0 + 1;       rank[j0 + 1] = basep + m0; }
        if (m2) { members[c * MAXM + basep + m0 + m1] = j0 + 2;  rank[j0 + 2] = basep + m0 + m1; }
        if (m3) { members[c * MAXM + basep + m0 + m1 + m2] = j0 + 3;
                  rank[j0 + 3] = basep + m0 + m1 + m2; }
        cum += __popcll(k0) + __popcll(k1) + __popcll(k2) + __popcll(k3);
    }
    if (tt == 0) cnt[c] = wcnt[0] + wcnt[1] + wcnt[2] + wcnt[3];
}

// stage one 128x128B fp8 A-panel + B-panel K-tile into LDS (4 waves, 8 loads/wave)
// placement: LDS[row][slot s] = global chunk sw02(s ^ (row&7))
__device__ __forceinline__ void stage_tile8(const unsigned char* __restrict__ E8,
                                            char* As, char* Bs,
                                            int row0, int col0, int k0,
                                            int w, int srow, int sk) {
#pragma unroll
    for (int q = 0; q < 4; ++q) {
        const char* ga = (const char*)(E8 + (size_t)(row0 + srow + q * 8) * D + k0) + sk;
        const char* gb = (const char*)(E8 + (size_t)(col0 + srow + q * 8) * D + k0) + sk;
        __builtin_amdgcn_global_load_lds(
            (const __attribute__((address_space(1))) unsigned int*)ga,
            (__attribute__((address_space(3))) unsigned int*)(As + w * 4096 + q * 1024),
            16, 0, 0);
        __builtin_amdgcn_global_load_lds(
            (const __attribute__((address_space(1))) unsigned int*)gb,
            (__attribute__((address_space(3))) unsigned int*)(Bs + w * 4096 + q * 1024),
            16, 0, 0);
    }
}

// ---------------- symmetric MX-fp8 MFMA masked-sum-exp + numerator scatter ----------------
// R13 structure exact (71 us known-good: 4 waves, 64x64 quadrants). New: the masked
// same-label elements ARE the numerator logits -- scatter them to nbuf[i*MAXM+rank[j]]
// (and the transposed slot for off-diagonal tiles). Each ordered same-label pair lies
// in exactly one tile-element -> every slot written exactly once (deterministic).
// Replaces the entire numer_mfma recompute kernel.
__global__ __launch_bounds__(256, 2) void lse_sym_kernel(const unsigned char* __restrict__ E8,
                                                         const int* __restrict__ labels,
                                                         const int* __restrict__ rank,
                                                         float* __restrict__ part,
                                                         float* __restrict__ nbuf) {
    __shared__ char As[128 * 128];   // 16 KB
    __shared__ char Bs[128 * 128];
    __shared__ float sh_r[4][64];
    __shared__ float sh_c[4][64];

    // XCD-chunked bijective swizzle: each XCD gets 260 consecutive triangle tiles
    int bid = (blockIdx.x & 7) * (NTRI / 8) + (blockIdx.x >> 3);
    int rb = 0, off = 0;
    while (off + (NRB - rb) <= bid) { off += NRB - rb; ++rb; }
    const int cb = rb + (bid - off);

    const int row0 = rb * 128;
    const int col0 = cb * 128;
    const int t    = threadIdx.x;
    const int lane = t & 63;
    const int w    = t >> 6;
    const int wr   = w >> 1;          // wave row quadrant (0..1)
    const int wc   = w & 1;           // wave col quadrant (0..1)

    int rlab[16];
#pragma unroll
    for (int m = 0; m < 4; ++m)
#pragma unroll
        for (int r = 0; r < 4; ++r)
            rlab[m * 4 + r] = labels[row0 + wr * 64 + m * 16 + ((lane >> 4) << 2) + r];
    int clab[4];
#pragma unroll
    for (int n = 0; n < 4; ++n) clab[n] = labels[col0 + wc * 64 + n * 16 + (lane & 15)];

    const int srow = w * 32 + (lane >> 3);
    const int sk   = sw02((lane & 7) ^ (lane >> 3)) << 4;   // inverse placement on source
    const int p    = lane >> 4;
    const int kq   = 2 * (p & 1) + (p >> 1);                // pi(p): quarter bijection
    const int swz  = (lane & 7) << 4;                       // (row&7)<<4, row&7 == lane&7
    const int loff = (kq << 4) ^ swz;                       // chunk 2p -> slot sw02(2p)^rho

    f32x4 acc[4][4];
#pragma unroll
    for (int m = 0; m < 4; ++m)
#pragma unroll
        for (int n = 0; n < 4; ++n) { f32x4 z = {0.f, 0.f, 0.f, 0.f}; acc[m][n] = z; }

    const int nt = D / 128;   // 8 K-tiles
    for (int kt = 0; kt < nt; ++kt) {
        __syncthreads();                       // prior tile's frag reads retired (WAR)
        stage_tile8(E8, As, Bs, row0, col0, kt * 128, w, srow, sk);
        __syncthreads();                       // vmcnt(0) drain: staged data visible

        i32x8 b[4];
#pragma unroll
        for (int n = 0; n < 4; ++n) {
            int row = wc * 64 + n * 16 + (lane & 15);
            const char* pb = Bs + row * 128;
            int4 lo = *(const int4*)(pb + loff);
            int4 hi = *(const int4*)(pb + (loff ^ 64));
            b[n][0] = lo.x; b[n][1] = lo.y; b[n][2] = lo.z; b[n][3] = lo.w;
            b[n][4] = hi.x; b[n][5] = hi.y; b[n][6] = hi.z; b[n][7] = hi.w;
        }

        __builtin_amdgcn_s_setprio(1);
#pragma unroll
        for (int m = 0; m < 4; ++m) {
            int row = wr * 64 + m * 16 + (lane & 15);
            const char* pa = As + row * 128;
            int4 lo = *(const int4*)(pa + loff);
            int4 hi = *(const int4*)(pa + (loff ^ 64));
            i32x8 a;
            a[0] = lo.x; a[1] = lo.y; a[2] = lo.z; a[3] = lo.w;
            a[4] = hi.x; a[5] = hi.y; a[6] = hi.z; a[7] = hi.w;
#pragma unroll
            for (int n = 0; n < 4; ++n)
                acc[m][n] = __builtin_amdgcn_mfma_scale_f32_16x16x128_f8f6f4(
                    a, b[n], acc[m][n], 0, 0, 0, 127, 0, 127);
        }
        __builtin_amdgcn_s_setprio(0);
    }

    // ranks for this thread's rows/cols (L2-resident; loaded after K-loop)
    int ranki[16], rankj[4];
#pragma unroll
    for (int m = 0; m < 4; ++m)
#pragma unroll
        for (int r = 0; r < 4; ++r)
            ranki[m * 4 + r] = rank[row0 + wr * 64 + m * 16 + ((lane >> 4) << 2) + r];
#pragma unroll
    for (int n = 0; n < 4; ++n) rankj[n] = rank[col0 + wc * 64 + n * 16 + (lane & 15)];

    // epilogue: masked exp + numerator scatter; reduce along BOTH axes
    float rsum[16];
#pragma unroll
    for (int i = 0; i < 16; ++i) rsum[i] = 0.f;
    float csum[4];
#pragma unroll
    for (int n = 0; n < 4; ++n) csum[n] = 0.f;

#pragma unroll
    for (int m = 0; m < 4; ++m)
#pragma unroll
        for (int n = 0; n < 4; ++n)
#pragma unroll
            for (int r = 0; r < 4; ++r) {
                float x = acc[m][n][r] * INV_T;
                bool same = (rlab[m * 4 + r] == clab[n]);
                float e = same ? 0.f : __expf(x - CMAX);
                rsum[m * 4 + r] += e;
                csum[n] += e;
                if (same) {
                    int gi = row0 + wr * 64 + m * 16 + ((lane >> 4) << 2) + r;
                    int gj = col0 + wc * 64 + n * 16 + (lane & 15);
                    nbuf[(size_t)gi * MAXM + rankj[n]] = x;
                    if (rb != cb) nbuf[(size_t)gj * MAXM + ranki[m * 4 + r]] = x;
                }
            }

#pragma unroll
    for (int o = 1; o < 16; o <<= 1)
#pragma unroll
        for (int i = 0; i < 16; ++i) rsum[i] += __shfl_xor(rsum[i], o);
    if ((lane & 15) == 0) {
#pragma unroll
        for (int m = 0; m < 4; ++m)
#pragma unroll
            for (int r = 0; r < 4; ++r)
                sh_r[w][m * 16 + ((lane >> 4) << 2) + r] = rsum[m * 4 + r];
    }
#pragma unroll
    for (int n = 0; n < 4; ++n) {
        csum[n] += __shfl_xor(csum[n], 16);
        csum[n] += __shfl_xor(csum[n], 32);
    }
    if (lane < 16) {
#pragma unroll
        for (int n = 0; n < 4; ++n) sh_c[w][n * 16 + lane] = csum[n];
    }
    __syncthreads();
    if (t < 128) {
        int wri = t >> 6, idx = t & 63;
        float s = sh_r[wri * 2][idx] + sh_r[wri * 2 + 1][idx];
        part[(size_t)(row0 + t) * NRB + cb] = s;
    } else if (rb != cb) {
        int c = t - 128;
        int wci = c >> 6, idx = c & 63;
        float s = sh_c[wci][idx] + sh_c[2 + wci][idx];
        part[(size_t)(col0 + c) * NRB + rb] = s;
    }
}

// ---------------- merge NRB partials -> base[i] = CMAX + log(sum) ----------------
__global__ __launch_bounds__(256) void combine_kernel(const float* __restrict__ part,
                                                      float* __restrict__ base) {
    int i = blockIdx.x * 256 + threadIdx.x;
    float s = 0.f;
#pragma unroll
    for (int k = 0; k < NRB; ++k) s += part[(size_t)i * NRB + k];
    base[i] = logf(s) + CMAX;
}

// ---------------- numerator from scattered logits: softplus(base_i - x) ----------------
// one wave per row i; slots s<n of nbuf[i] hold the logits vs class members (s==rank[i]
// is the diagonal, skipped). Coalesced row-contiguous reads.
__global__ __launch_bounds__(256) void numer_softplus_kernel(const int* __restrict__ labels,
                                                             const int* __restrict__ cnt,
                                                             const int* __restrict__ rank,
                                                             const float* __restrict__ base,
                                                             const float* __restrict__ nbuf,
                                                             float* __restrict__ rowpart) {
    const int i = blockIdx.x * 4 + (threadIdx.x >> 6);
    const int lane = threadIdx.x & 63;
    const int li = labels[i];
    const int n  = cnt[li];
    const int ri = rank[i];
    const float bi = base[i];
    float acc = 0.f;
    for (int s = lane; s < n; s += 64) {
        if (s != ri) {
            float d = bi - nbuf[(size_t)i * MAXM + s];
            acc += (d > 15.f) ? d : log1pf(__expf(d));
        }
    }
#pragma unroll
    for (int o = 32; o > 0; o >>= 1) acc += __shfl_xor(acc, o);
    if (lane == 0) rowpart[i] = (n > 1) ? acc / (float)(n - 1) : 0.f;
}

// ---------------- final deterministic reduction ----------------
__global__ __launch_bounds__(256) void final_kernel(const float* __restrict__ rowpart,
                                                    float* __restrict__ out) {
    __shared__ float red[256];
    int t = threadIdx.x;
    float acc = 0.f;
    for (int k = 0; k < B / 256; ++k) acc += rowpart[t + k * 256];
    red[t] = acc;
    __syncthreads();
    for (int g = 128; g > 0; g >>= 1) {
        if (t < g) red[t] += red[t + g];
        __syncthreads();
    }
    if (t == 0) out[0] = red[0] / (float)B;
}

// ================= fp32 fallback path (known-good) =================
#define BR 64
#define BC 64
#define KT 32
#define PAD 68
__global__ __launch_bounds__(256) void class_list_kernel(const int* __restrict__ labels,
                                                         int* __restrict__ members,
                                                         int* __restrict__ cnt) {
    const int c = blockIdx.x;
    const int tt = threadIdx.x;
    const int lane = tt & 63, w = tt >> 6;
    __shared__ int wcnt[4];
    int cw = 0;
    for (int b0 = w * 2048; b0 < (w + 1) * 2048; b0 += 64)
        cw += __popcll(__ballot(labels[b0 + lane] == c));
    if (lane == 0) wcnt[w] = cw;
    __syncthreads();
    int cum = 0;
    for (int x = 0; x < w; ++x) cum += wcnt[x];
    for (int b0 = w * 2048; b0 < (w + 1) * 2048; b0 += 64) {
        bool match = (labels[b0 + lane] == c);
        unsigned long long mask = __ballot(match);
        int pre = __popcll(mask & ((1ull << lane) - 1ull));
        if (match) members[c * MAXM + cum + pre] = b0 + lane;
        cum += __popcll(mask);
    }
    if (tt == 0) cnt[c] = wcnt[0] + wcnt[1] + wcnt[2] + wcnt[3];
}
__global__ __launch_bounds__(256) void lse_f32_kernel(const float* __restrict__ E,
                                                      const int* __restrict__ labels,
                                                      float2* __restrict__ part) {
    __shared__ float As[KT][PAD];
    __shared__ float Bs[KT][PAD];
    __shared__ int   clabs[BC];
    __shared__ float msh[BR][16];
    __shared__ float ssh[BR][16];
    const int rb = blockIdx.x, cs = blockIdx.y;
    const int row0 = rb * BR;
    const int t = threadIdx.x;
    const int tx = t & 15, ty = t >> 4;
    int rlab[4];
#pragma unroll
    for (int i = 0; i < 4; ++i) rlab[i] = labels[row0 + ty * 4 + i];
    float m[4], s[4];
#pragma unroll
    for (int i = 0; i < 4; ++i) { m[i] = -INFINITY; s[i] = 0.f; }
    for (int ct = 0; ct < CW / BC; ++ct) {
        const int col0 = cs * CW + ct * BC;
        __syncthreads();
        if (t < BC) clabs[t] = labels[col0 + t];
        float acc[4][4];
#pragma unroll
        for (int i = 0; i < 4; ++i)
#pragma unroll
            for (int j = 0; j < 4; ++j) acc[i][j] = 0.f;
        for (int k0 = 0; k0 < D; k0 += KT) {
            __syncthreads();
#pragma unroll
            for (int q = 0; q < 2; ++q) {
                int id = q * 256 + t, row = id >> 3, kk = (id & 7) * 4;
                float4 va = *(const float4*)&E[(size_t)(row0 + row) * D + k0 + kk];
                As[kk + 0][row] = va.x; As[kk + 1][row] = va.y;
                As[kk + 2][row] = va.z; As[kk + 3][row] = va.w;
                float4 vb = *(const float4*)&E[(size_t)(col0 + row) * D + k0 + kk];
                Bs[kk + 0][row] = vb.x; Bs[kk + 1][row] = vb.y;
                Bs[kk + 2][row] = vb.z; Bs[kk + 3][row] = vb.w;
            }
            __syncthreads();
#pragma unroll
            for (int kk = 0; kk < KT; ++kk) {
                float4 av = *(const float4*)&As[kk][ty * 4];
                float4 bv = *(const float4*)&Bs[kk][tx * 4];
                float a_[4] = {av.x, av.y, av.z, av.w};
                float b_[4] = {bv.x, bv.y, bv.z, bv.w};
#pragma unroll
                for (int i = 0; i < 4; ++i)
#pragma unroll
                    for (int j = 0; j < 4; ++j) acc[i][j] += a_[i] * b_[j];
            }
        }
#pragma unroll
        for (int j = 0; j < 4; ++j) {
            int cl = clabs[tx * 4 + j];
#pragma unroll
            for (int i = 0; i < 4; ++i) {
                if (rlab[i] != cl) {
                    float x = acc[i][j] * INV_T;
                    if (x > m[i]) { s[i] = s[i] * __expf(m[i] - x) + 1.f; m[i] = x; }
                    else           s[i] += __expf(x - m[i]);
                }
            }
        }
    }
    __syncthreads();
#pragma unroll
    for (int i = 0; i < 4; ++i) { msh[ty * 4 + i][tx] = m[i]; ssh[ty * 4 + i][tx] = s[i]; }
    __syncthreads();
    if (t < BR) {
        float M = -INFINITY, S = 0.f;
#pragma unroll
        for (int x = 0; x < 16; ++x) {
            float pm = msh[t][x], ps = ssh[t][x];
            if (pm > M)             { S = S * __expf(M - pm) + ps; M = pm; }
            else if (pm > -INFINITY)  S += ps * __expf(pm - M);
        }
        part[(size_t)(row0 + t) * SPLITS + cs] = make_float2(M, S);
    }
}
__global__ __launch_bounds__(256) void combine_f32_kernel(const float2* __restrict__ part,
                                                          float* __restrict__ base) {
    int i = blockIdx.x * 256 + threadIdx.x;
    if (i >= B) return;
    float M = -INFINITY, S = 0.f;
#pragma unroll
    for (int k = 0; k < SPLITS; ++k) {
        float2 p = part[(size_t)i * SPLITS + k];
        if (p.x > M)             { S = S * __expf(M - p.x) + p.y; M = p.x; }
        else if (p.x > -INFINITY)  S += p.y * __expf(p.x - M);
    }
    base[i] = M + logf(S);
}
__global__ __launch_bounds__(256) void numer_kernel(const float* __restrict__ E,
                                                    const int* __restrict__ labels,
                                                    const float* __restrict__ base,
                                                    const int* __restrict__ members,
                                                    const int* __restrict__ cnt,
                                                    float* __restrict__ rowpart) {
    const int i = blockIdx.x;
    const int t = threadIdx.x;
    const int lane = t & 63, w = t >> 6;
    __shared__ float ei[D];
    __shared__ float wacc[4];
    ((float4*)ei)[t] = ((const float4*)(E + (size_t)i * D))[t];
    const int   li = labels[i];
    const float bi = base[i];
    const int   n  = cnt[li];
    __syncthreads();
    float acc = 0.f;
    const float4* U = (const float4*)ei;
    for (int s = w; s < n; s += 4) {
        int j = members[li * MAXM + s];
        if (j == i) continue;
        const float4* Ej = (const float4*)(E + (size_t)j * D);
        float d = 0.f;
#pragma unroll
        for (int q = 0; q < 4; ++q) {
            float4 v = Ej[lane + 64 * q];
            float4 u = U[lane + 64 * q];
            d += v.x * u.x + v.y * u.y + v.z * u.z + v.w * u.w;
        }
#pragma unroll
        for (int o = 32; o > 0; o >>= 1) d += __shfl_xor(d, o);
        if (lane == 0) {
            float x = bi - d * INV_T;
            acc += (x > 15.f) ? x : log1pf(__expf(x));
        }
    }
    if (lane == 0) wacc[w] = acc;
    __syncthreads();
    if (t == 0) {
        float a = wacc[0] + wacc[1] + wacc[2] + wacc[3];
        rowpart[i] = (n > 1) ? a / (float)(n - 1) : 0.f;
    }
}

extern "C" void kernel_launch(void* const* d_in, const int* in_sizes, int n_in,
                              void* d_out, int out_size, void* d_ws, size_t ws_size,
                              hipStream_t stream) {
    const float* E      = (const float*)d_in[0];
    const int*   labels = (const int*)d_in[1];
    float*       out    = (float*)d_out;

    const size_t szE8   = (size_t)B * D;              // 8 MB
    const size_t szPart = (size_t)B * NRB * 4;        // 2 MB
    const size_t szNbuf = (size_t)B * MAXM * 4;       // 8 MB
    const size_t need   = szE8 + szPart + szNbuf + 4 * B + 4 * B + 4 * B
                        + 4 * NCLS * MAXM + 4 * NCLS + 512;

    if (ws_size >= need) {
        char* ws = (char*)d_ws;
        unsigned char* E8 = (unsigned char*)ws;  ws += szE8;
        float* part    = (float*)ws;   ws += szPart;
        float* nbuf    = (float*)ws;   ws += szNbuf;
        float* base    = (float*)ws;   ws += 4 * B;
        float* rowpart = (float*)ws;   ws += 4 * B;
        int*   rank    = (int*)ws;     ws += 4 * B;
        int*   members = (int*)ws;     ws += 4 * NCLS * MAXM;
        int*   cnt     = (int*)ws;     ws += 4 * NCLS;

        convert_classlist_kernel<<<NCONV + NCLS, 256, 0, stream>>>(E, E8, labels, members, cnt, rank);
        lse_sym_kernel<<<NTRI, 256, 0, stream>>>(E8, labels, rank, part, nbuf);
        combine_kernel<<<B / 256, 256, 0, stream>>>(part, base);
        numer_softplus_kernel<<<B / 4, 256, 0, stream>>>(labels, cnt, rank, base, nbuf, rowpart);
        final_kernel<<<1, 256, 0, stream>>>(rowpart, out);
    } else {
        char* ws = (char*)d_ws;
        float2* part   = (float2*)ws;  ws += sizeof(float2) * B * SPLITS;
        float* base    = (float*)ws;   ws += 4 * B;
        float* rowpart = (float*)ws;   ws += 4 * B;
        int*   members = (int*)ws;     ws += 4 * NCLS * MAXM;
        int*   cnt     = (int*)ws;

        lse_f32_kernel<<<dim3(B / BR, SPLITS), 256, 0, stream>>>(E, labels, part);
        combine_f32_kernel<<<B / 256, 256, 0, stream>>>(part, base);
        class_list_kernel<<<NCLS, 256, 0, stream>>>(labels, members, cnt);
        numer_kernel<<<B, 256, 0, stream>>>(E, labels, base, members, cnt, rowpart);
        final_kernel<<<1, 256, 0, stream>>>(rowpart, out);
    }
}

// Round 18
// 93.577 us; speedup vs baseline: 5.9374x; 5.9374x over previous
//
#include <hip/hip_runtime.h>
#include <math.h>

#define B 8192
#define D 1024
#define INV_T (1.0f/0.07f)
#define CMAX (1.0f/0.07f)   // upper bound on any logit (unit-norm rows): fixed LSE max
#define SPLITS 8
#define CW (B/SPLITS)
#define MAXM 256            // max class size (mean 82)
#define NCLS 100
#define NRB (B/128)         // 64 row blocks
#define NTRI (NRB*(NRB+1)/2) // 2080 triangular tiles (2080 % 8 == 0)
#define NCONV (B*D/4/256)   // 8192 convert blocks

typedef __attribute__((ext_vector_type(4))) float  f32x4;
typedef __attribute__((ext_vector_type(8))) int    i32x8;

// swap bits 0 and 2 (involution on 0..7) -- chunk<->slot permutation
__device__ __forceinline__ int sw02(int x) {
    return (x & 2) | ((x & 1) << 2) | ((x >> 2) & 1);
}

// ---------------- fused: fp32->fp8 convert (blocks 0..8191) + per-class lists ----------------
__global__ __launch_bounds__(256) void convert_classlist_kernel(const float* __restrict__ E,
                                                                unsigned char* __restrict__ E8,
                                                                const int* __restrict__ labels,
                                                                int* __restrict__ members,
                                                                int* __restrict__ cnt) {
    if (blockIdx.x < NCONV) {
        int i = blockIdx.x * 256 + threadIdx.x;          // covers B*D/4
        float4 v = ((const float4*)E)[i];
        int lo = __builtin_amdgcn_cvt_pk_fp8_f32(v.x, v.y, 0, false);   // bytes 0,1
        int pk = __builtin_amdgcn_cvt_pk_fp8_f32(v.z, v.w, lo, true);   // bytes 2,3
        ((int*)E8)[i] = pk;
        return;
    }
    const int c  = blockIdx.x - NCONV;
    const int tt = threadIdx.x;
    const int lane = tt & 63, w = tt >> 6;
    __shared__ int wcnt[4];
    int cw = 0;
    for (int b0 = w * 2048; b0 < (w + 1) * 2048; b0 += 256) {
        int4 lv = ((const int4*)labels)[(b0 >> 2) + lane];
        cw += __popcll(__ballot(lv.x == c)) + __popcll(__ballot(lv.y == c))
            + __popcll(__ballot(lv.z == c)) + __popcll(__ballot(lv.w == c));
    }
    if (lane == 0) wcnt[w] = cw;
    __syncthreads();
    int cum = 0;
    for (int x = 0; x < w; ++x) cum += wcnt[x];
    for (int b0 = w * 2048; b0 < (w + 1) * 2048; b0 += 256) {
        int4 lv = ((const int4*)labels)[(b0 >> 2) + lane];
        unsigned long long k0 = __ballot(lv.x == c), k1 = __ballot(lv.y == c);
        unsigned long long k2 = __ballot(lv.z == c), k3 = __ballot(lv.w == c);
        unsigned long long below = (1ull << lane) - 1ull;
        int prelane = __popcll(k0 & below) + __popcll(k1 & below)
                    + __popcll(k2 & below) + __popcll(k3 & below);
        int m0 = (lv.x == c), m1 = (lv.y == c), m2 = (lv.z == c), m3 = (lv.w == c);
        int basep = cum + prelane;
        int j0 = b0 + 4 * lane;
        if (m0) members[c * MAXM + basep] = j0;
        if (m1) members[c * MAXM + basep + m0] = j0 + 1;
        if (m2) members[c * MAXM + basep + m0 + m1] = j0 + 2;
        if (m3) members[c * MAXM + basep + m0 + m1 + m2] = j0 + 3;
        cum += __popcll(k0) + __popcll(k1) + __popcll(k2) + __popcll(k3);
    }
    if (tt == 0) cnt[c] = wcnt[0] + wcnt[1] + wcnt[2] + wcnt[3];
}

// stage one 128x128B fp8 A-panel + B-panel K-tile into LDS (4+4 loads/wave)
// placement: LDS[row][slot s] = global chunk sw02(s ^ (row&7))
__device__ __forceinline__ void stage_tile8(const unsigned char* __restrict__ E8,
                                            char* As, char* Bs,
                                            int row0, int col0, int k0,
                                            int w, int srow, int sk) {
#pragma unroll
    for (int q = 0; q < 4; ++q) {
        const char* ga = (const char*)(E8 + (size_t)(row0 + srow + q * 8) * D + k0) + sk;
        const char* gb = (const char*)(E8 + (size_t)(col0 + srow + q * 8) * D + k0) + sk;
        __builtin_amdgcn_global_load_lds(
            (const __attribute__((address_space(1))) unsigned int*)ga,
            (__attribute__((address_space(3))) unsigned int*)(As + w * 4096 + q * 1024),
            16, 0, 0);
        __builtin_amdgcn_global_load_lds(
            (const __attribute__((address_space(1))) unsigned int*)gb,
            (__attribute__((address_space(3))) unsigned int*)(Bs + w * 4096 + q * 1024),
            16, 0, 0);
    }
}

// ---------------- symmetric MX-fp8 MFMA masked-sum-exp (R13 known-good, 71 us) ----------------
// R14: direct-global frags 2x worse (address divergence). R16: 8-wave smaller tiles
// worse (1.5x LDS ops, occupancy unmoved). R17: numerator scatter-fusion 7x worse
// (write-allocate evicts E8 from L2 -> 1.3 GB refetch). This 4-wave 64x64 LDS-staged
// structure is the verified optimum.
__global__ __launch_bounds__(256, 2) void lse_sym_kernel(const unsigned char* __restrict__ E8,
                                                         const int* __restrict__ labels,
                                                         float* __restrict__ part) {
    __shared__ char As[128 * 128];   // 16 KB
    __shared__ char Bs[128 * 128];
    __shared__ float sh_r[4][64];
    __shared__ float sh_c[4][64];

    // XCD-chunked bijective swizzle: each XCD gets 260 consecutive triangle tiles
    int bid = (blockIdx.x & 7) * (NTRI / 8) + (blockIdx.x >> 3);
    int rb = 0, off = 0;
    while (off + (NRB - rb) <= bid) { off += NRB - rb; ++rb; }
    const int cb = rb + (bid - off);

    const int row0 = rb * 128;
    const int col0 = cb * 128;
    const int t    = threadIdx.x;
    const int lane = t & 63;
    const int w    = t >> 6;
    const int wr   = w >> 1;          // wave row quadrant (0..1)
    const int wc   = w & 1;           // wave col quadrant (0..1)

    int rlab[16];
#pragma unroll
    for (int m = 0; m < 4; ++m)
#pragma unroll
        for (int r = 0; r < 4; ++r)
            rlab[m * 4 + r] = labels[row0 + wr * 64 + m * 16 + ((lane >> 4) << 2) + r];
    int clab[4];
#pragma unroll
    for (int n = 0; n < 4; ++n) clab[n] = labels[col0 + wc * 64 + n * 16 + (lane & 15)];

    const int srow = w * 32 + (lane >> 3);
    const int sk   = sw02((lane & 7) ^ (lane >> 3)) << 4;   // inverse placement on source
    const int p    = lane >> 4;
    const int kq   = 2 * (p & 1) + (p >> 1);                // pi(p): quarter bijection
    const int swz  = (lane & 7) << 4;                       // (row&7)<<4, row&7 == lane&7
    const int loff = (kq << 4) ^ swz;                       // chunk 2p -> slot sw02(2p)^rho

    f32x4 acc[4][4];
#pragma unroll
    for (int m = 0; m < 4; ++m)
#pragma unroll
        for (int n = 0; n < 4; ++n) { f32x4 z = {0.f, 0.f, 0.f, 0.f}; acc[m][n] = z; }

    const int nt = D / 128;   // 8 K-tiles
    for (int kt = 0; kt < nt; ++kt) {
        __syncthreads();                       // prior tile's frag reads retired (WAR)
        stage_tile8(E8, As, Bs, row0, col0, kt * 128, w, srow, sk);
        __syncthreads();                       // vmcnt(0) drain: staged data visible

        i32x8 b[4];
#pragma unroll
        for (int n = 0; n < 4; ++n) {
            int row = wc * 64 + n * 16 + (lane & 15);
            const char* pb = Bs + row * 128;
            int4 lo = *(const int4*)(pb + loff);
            int4 hi = *(const int4*)(pb + (loff ^ 64));
            b[n][0] = lo.x; b[n][1] = lo.y; b[n][2] = lo.z; b[n][3] = lo.w;
            b[n][4] = hi.x; b[n][5] = hi.y; b[n][6] = hi.z; b[n][7] = hi.w;
        }

        __builtin_amdgcn_s_setprio(1);
#pragma unroll
        for (int m = 0; m < 4; ++m) {
            int row = wr * 64 + m * 16 + (lane & 15);
            const char* pa = As + row * 128;
            int4 lo = *(const int4*)(pa + loff);
            int4 hi = *(const int4*)(pa + (loff ^ 64));
            i32x8 a;
            a[0] = lo.x; a[1] = lo.y; a[2] = lo.z; a[3] = lo.w;
            a[4] = hi.x; a[5] = hi.y; a[6] = hi.z; a[7] = hi.w;
#pragma unroll
            for (int n = 0; n < 4; ++n)
                acc[m][n] = __builtin_amdgcn_mfma_scale_f32_16x16x128_f8f6f4(
                    a, b[n], acc[m][n], 0, 0, 0, 127, 0, 127);
        }
        __builtin_amdgcn_s_setprio(0);
    }

    // epilogue: masked exp once per element; reduce along BOTH axes
    float rsum[16];
#pragma unroll
    for (int i = 0; i < 16; ++i) rsum[i] = 0.f;
    float csum[4];
#pragma unroll
    for (int n = 0; n < 4; ++n) csum[n] = 0.f;

#pragma unroll
    for (int m = 0; m < 4; ++m)
#pragma unroll
        for (int n = 0; n < 4; ++n)
#pragma unroll
            for (int r = 0; r < 4; ++r) {
                float x = acc[m][n][r] * INV_T;
                float e = (rlab[m * 4 + r] != clab[n]) ? __expf(x - CMAX) : 0.f;
                rsum[m * 4 + r] += e;
                csum[n] += e;
            }

#pragma unroll
    for (int o = 1; o < 16; o <<= 1)
#pragma unroll
        for (int i = 0; i < 16; ++i) rsum[i] += __shfl_xor(rsum[i], o);
    if ((lane & 15) == 0) {
#pragma unroll
        for (int m = 0; m < 4; ++m)
#pragma unroll
            for (int r = 0; r < 4; ++r)
                sh_r[w][m * 16 + ((lane >> 4) << 2) + r] = rsum[m * 4 + r];
    }
#pragma unroll
    for (int n = 0; n < 4; ++n) {
        csum[n] += __shfl_xor(csum[n], 16);
        csum[n] += __shfl_xor(csum[n], 32);
    }
    if (lane < 16) {
#pragma unroll
        for (int n = 0; n < 4; ++n) sh_c[w][n * 16 + lane] = csum[n];
    }
    __syncthreads();
    if (t < 128) {
        int wri = t >> 6, idx = t & 63;
        float s = sh_r[wri * 2][idx] + sh_r[wri * 2 + 1][idx];
        part[(size_t)(row0 + t) * NRB + cb] = s;
    } else if (rb != cb) {
        int c = t - 128;
        int wci = c >> 6, idx = c & 63;
        float s = sh_c[wci][idx] + sh_c[2 + wci][idx];
        part[(size_t)(col0 + c) * NRB + rb] = s;
    }
}

// ---------------- merge NRB partials -> base[i] = CMAX + log(sum) ----------------
__global__ __launch_bounds__(256) void combine_kernel(const float* __restrict__ part,
                                                      float* __restrict__ base) {
    int i = blockIdx.x * 256 + threadIdx.x;
    float s = 0.f;
#pragma unroll
    for (int k = 0; k < NRB; ++k) s += part[(size_t)i * NRB + k];
    base[i] = logf(s) + CMAX;
}

// ---------------- numerator: per-class MX-fp8 MFMA Gram tiles (R13) ----------------
__global__ __launch_bounds__(256) void numer_mfma_kernel(const unsigned char* __restrict__ E8,
                                                         const float* __restrict__ base,
                                                         const int* __restrict__ members,
                                                         const int* __restrict__ cnt,
                                                         float* __restrict__ part2) {
    const int c  = blockIdx.x;
    const int rt = blockIdx.y;
    const int ctile = blockIdx.z;
    const int t    = threadIdx.x;
    const int lane = t & 63;
    const int w    = t >> 6;
    const int n    = cnt[c];
    const int pidx = c * 16 + rt * 4 + ctile;

    __shared__ char As[64 * 128];   // 8 KB
    __shared__ char Bs[64 * 128];
    __shared__ float red[256];

    if (rt * 64 >= n || ctile * 64 >= n) {
        if (t == 0) part2[pidx] = 0.f;
        return;
    }

    int gi[4]; float bi[4]; bool iv[4];
#pragma unroll
    for (int r = 0; r < 4; ++r) {
        int il = rt * 64 + w * 16 + ((lane >> 4) << 2) + r;
        iv[r] = (il < n);
        int idx = members[c * MAXM + (iv[r] ? il : 0)];
        gi[r] = il;
        bi[r] = base[idx];
    }
    int gj[4]; bool jv[4];
#pragma unroll
    for (int nn = 0; nn < 4; ++nn) {
        int jl = ctile * 64 + nn * 16 + (lane & 15);
        jv[nn] = (jl < n);
        gj[nn] = jl;
    }

    const int lr   = (lane >> 3);
    const int sk   = sw02((lane & 7) ^ lr) << 4;
    const int pp   = lane >> 4;
    const int kq   = 2 * (pp & 1) + (pp >> 1);
    const int swz  = (lane & 7) << 4;
    const int loff = (kq << 4) ^ swz;

    int arow[2], brow[2];
#pragma unroll
    for (int q = 0; q < 2; ++q) {
        int al = rt * 64 + w * 16 + q * 8 + lr;
        int bl = ctile * 64 + w * 16 + q * 8 + lr;
        arow[q] = members[c * MAXM + ((al < n) ? al : 0)];
        brow[q] = members[c * MAXM + ((bl < n) ? bl : 0)];
    }

    f32x4 acc[4];
#pragma unroll
    for (int nn = 0; nn < 4; ++nn) { f32x4 z = {0.f, 0.f, 0.f, 0.f}; acc[nn] = z; }

    for (int kt = 0; kt < D / 128; ++kt) {
        __syncthreads();
#pragma unroll
        for (int q = 0; q < 2; ++q) {
            const char* ga = (const char*)(E8 + (size_t)arow[q] * D + kt * 128) + sk;
            const char* gb = (const char*)(E8 + (size_t)brow[q] * D + kt * 128) + sk;
            __builtin_amdgcn_global_load_lds(
                (const __attribute__((address_space(1))) unsigned int*)ga,
                (__attribute__((address_space(3))) unsigned int*)(As + w * 2048 + q * 1024),
                16, 0, 0);
            __builtin_amdgcn_global_load_lds(
                (const __attribute__((address_space(1))) unsigned int*)gb,
                (__attribute__((address_space(3))) unsigned int*)(Bs + w * 2048 + q * 1024),
                16, 0, 0);
        }
        __syncthreads();

        i32x8 a, b[4];
        {
            int row = w * 16 + (lane & 15);
            const char* pa = As + row * 128;
            int4 lo = *(const int4*)(pa + loff);
            int4 hi = *(const int4*)(pa + (loff ^ 64));
            a[0] = lo.x; a[1] = lo.y; a[2] = lo.z; a[3] = lo.w;
            a[4] = hi.x; a[5] = hi.y; a[6] = hi.z; a[7] = hi.w;
        }
#pragma unroll
        for (int nn = 0; nn < 4; ++nn) {
            int row = nn * 16 + (lane & 15);
            const char* pb = Bs + row * 128;
            int4 lo = *(const int4*)(pb + loff);
            int4 hi = *(const int4*)(pb + (loff ^ 64));
            b[nn][0] = lo.x; b[nn][1] = lo.y; b[nn][2] = lo.z; b[nn][3] = lo.w;
            b[nn][4] = hi.x; b[nn][5] = hi.y; b[nn][6] = hi.z; b[nn][7] = hi.w;
        }
#pragma unroll
        for (int nn = 0; nn < 4; ++nn)
            acc[nn] = __builtin_amdgcn_mfma_scale_f32_16x16x128_f8f6f4(
                a, b[nn], acc[nn], 0, 0, 0, 127, 0, 127);
    }

    float psum = 0.f;
#pragma unroll
    for (int nn = 0; nn < 4; ++nn)
#pragma unroll
        for (int r = 0; r < 4; ++r) {
            if (iv[r] && jv[nn] && gi[r] != gj[nn]) {
                float x = bi[r] - acc[nn][r] * INV_T;
                psum += (x > 15.f) ? x : log1pf(__expf(x));
            }
        }
    red[t] = psum;
    __syncthreads();
    for (int g = 128; g > 0; g >>= 1) {
        if (t < g) red[t] += red[t + g];
        __syncthreads();
    }
    if (t == 0) part2[pidx] = red[0];
}

// ---------------- final: scale per class by 1/(n_c-1), deterministic sum ----------------
__global__ __launch_bounds__(256) void final2_kernel(const float* __restrict__ part2,
                                                     const int* __restrict__ cnt,
                                                     float* __restrict__ out) {
    __shared__ float red[256];
    int t = threadIdx.x;
    float acc = 0.f;
    for (int p = t; p < NCLS * 16; p += 256) {
        int c = p >> 4;
        float wgt = (cnt[c] > 1) ? 1.f / (float)(cnt[c] - 1) : 0.f;
        acc += part2[p] * wgt;
    }
    red[t] = acc;
    __syncthreads();
    for (int g = 128; g > 0; g >>= 1) {
        if (t < g) red[t] += red[t + g];
        __syncthreads();
    }
    if (t == 0) out[0] = red[0] / (float)B;
}

// ================= fp32 fallback path (known-good) =================
#define BR 64
#define BC 64
#define KT 32
#define PAD 68
__global__ __launch_bounds__(256) void class_list_kernel(const int* __restrict__ labels,
                                                         int* __restrict__ members,
                                                         int* __restrict__ cnt) {
    const int c = blockIdx.x;
    const int tt = threadIdx.x;
    const int lane = tt & 63, w = tt >> 6;
    __shared__ int wcnt[4];
    int cw = 0;
    for (int b0 = w * 2048; b0 < (w + 1) * 2048; b0 += 64)
        cw += __popcll(__ballot(labels[b0 + lane] == c));
    if (lane == 0) wcnt[w] = cw;
    __syncthreads();
    int cum = 0;
    for (int x = 0; x < w; ++x) cum += wcnt[x];
    for (int b0 = w * 2048; b0 < (w + 1) * 2048; b0 += 64) {
        bool match = (labels[b0 + lane] == c);
        unsigned long long mask = __ballot(match);
        int pre = __popcll(mask & ((1ull << lane) - 1ull));
        if (match) members[c * MAXM + cum + pre] = b0 + lane;
        cum += __popcll(mask);
    }
    if (tt == 0) cnt[c] = wcnt[0] + wcnt[1] + wcnt[2] + wcnt[3];
}
__global__ __launch_bounds__(256) void lse_f32_kernel(const float* __restrict__ E,
                                                      const int* __restrict__ labels,
                                                      float2* __restrict__ part) {
    __shared__ float As[KT][PAD];
    __shared__ float Bs[KT][PAD];
    __shared__ int   clabs[BC];
    __shared__ float msh[BR][16];
    __shared__ float ssh[BR][16];
    const int rb = blockIdx.x, cs = blockIdx.y;
    const int row0 = rb * BR;
    const int t = threadIdx.x;
    const int tx = t & 15, ty = t >> 4;
    int rlab[4];
#pragma unroll
    for (int i = 0; i < 4; ++i) rlab[i] = labels[row0 + ty * 4 + i];
    float m[4], s[4];
#pragma unroll
    for (int i = 0; i < 4; ++i) { m[i] = -INFINITY; s[i] = 0.f; }
    for (int ct = 0; ct < CW / BC; ++ct) {
        const int col0 = cs * CW + ct * BC;
        __syncthreads();
        if (t < BC) clabs[t] = labels[col0 + t];
        float acc[4][4];
#pragma unroll
        for (int i = 0; i < 4; ++i)
#pragma unroll
            for (int j = 0; j < 4; ++j) acc[i][j] = 0.f;
        for (int k0 = 0; k0 < D; k0 += KT) {
            __syncthreads();
#pragma unroll
            for (int q = 0; q < 2; ++q) {
                int id = q * 256 + t, row = id >> 3, kk = (id & 7) * 4;
                float4 va = *(const float4*)&E[(size_t)(row0 + row) * D + k0 + kk];
                As[kk + 0][row] = va.x; As[kk + 1][row] = va.y;
                As[kk + 2][row] = va.z; As[kk + 3][row] = va.w;
                float4 vb = *(const float4*)&E[(size_t)(col0 + row) * D + k0 + kk];
                Bs[kk + 0][row] = vb.x; Bs[kk + 1][row] = vb.y;
                Bs[kk + 2][row] = vb.z; Bs[kk + 3][row] = vb.w;
            }
            __syncthreads();
#pragma unroll
            for (int kk = 0; kk < KT; ++kk) {
                float4 av = *(const float4*)&As[kk][ty * 4];
                float4 bv = *(const float4*)&Bs[kk][tx * 4];
                float a_[4] = {av.x, av.y, av.z, av.w};
                float b_[4] = {bv.x, bv.y, bv.z, bv.w};
#pragma unroll
                for (int i = 0; i < 4; ++i)
#pragma unroll
                    for (int j = 0; j < 4; ++j) acc[i][j] += a_[i] * b_[j];
            }
        }
#pragma unroll
        for (int j = 0; j < 4; ++j) {
            int cl = clabs[tx * 4 + j];
#pragma unroll
            for (int i = 0; i < 4; ++i) {
                if (rlab[i] != cl) {
                    float x = acc[i][j] * INV_T;
                    if (x > m[i]) { s[i] = s[i] * __expf(m[i] - x) + 1.f; m[i] = x; }
                    else           s[i] += __expf(x - m[i]);
                }
            }
        }
    }
    __syncthreads();
#pragma unroll
    for (int i = 0; i < 4; ++i) { msh[ty * 4 + i][tx] = m[i]; ssh[ty * 4 + i][tx] = s[i]; }
    __syncthreads();
    if (t < BR) {
        float M = -INFINITY, S = 0.f;
#pragma unroll
        for (int x = 0; x < 16; ++x) {
            float pm = msh[t][x], ps = ssh[t][x];
            if (pm > M)             { S = S * __expf(M - pm) + ps; M = pm; }
            else if (pm > -INFINITY)  S += ps * __expf(pm - M);
        }
        part[(size_t)(row0 + t) * SPLITS + cs] = make_float2(M, S);
    }
}
__global__ __launch_bounds__(256) void combine_f32_kernel(const float2* __restrict__ part,
                                                          float* __restrict__ base) {
    int i = blockIdx.x * 256 + threadIdx.x;
    if (i >= B) return;
    float M = -INFINITY, S = 0.f;
#pragma unroll
    for (int k = 0; k < SPLITS; ++k) {
        float2 p = part[(size_t)i * SPLITS + k];
        if (p.x > M)             { S = S * __expf(M - p.x) + p.y; M = p.x; }
        else if (p.x > -INFINITY)  S += p.y * __expf(p.x - M);
    }
    base[i] = M + logf(S);
}
__global__ __launch_bounds__(256) void numer_kernel(const float* __restrict__ E,
                                                    const int* __restrict__ labels,
                                                    const float* __restrict__ base,
                                                    const int* __restrict__ members,
                                                    const int* __restrict__ cnt,
                                                    float* __restrict__ rowpart) {
    const int i = blockIdx.x;
    const int t = threadIdx.x;
    const int lane = t & 63, w = t >> 6;
    __shared__ float ei[D];
    __shared__ float wacc[4];
    ((float4*)ei)[t] = ((const float4*)(E + (size_t)i * D))[t];
    const int   li = labels[i];
    const float bi = base[i];
    const int   n  = cnt[li];
    __syncthreads();
    float acc = 0.f;
    const float4* U = (const float4*)ei;
    for (int s = w; s < n; s += 4) {
        int j = members[li * MAXM + s];
        if (j == i) continue;
        const float4* Ej = (const float4*)(E + (size_t)j * D);
        float d = 0.f;
#pragma unroll
        for (int q = 0; q < 4; ++q) {
            float4 v = Ej[lane + 64 * q];
            float4 u = U[lane + 64 * q];
            d += v.x * u.x + v.y * u.y + v.z * u.z + v.w * u.w;
        }
#pragma unroll
        for (int o = 32; o > 0; o >>= 1) d += __shfl_xor(d, o);
        if (lane == 0) {
            float x = bi - d * INV_T;
            acc += (x > 15.f) ? x : log1pf(__expf(x));
        }
    }
    if (lane == 0) wacc[w] = acc;
    __syncthreads();
    if (t == 0) {
        float a = wacc[0] + wacc[1] + wacc[2] + wacc[3];
        rowpart[i] = (n > 1) ? a / (float)(n - 1) : 0.f;
    }
}
__global__ __launch_bounds__(256) void final_kernel(const float* __restrict__ rowpart,
                                                    float* __restrict__ out) {
    __shared__ float red[256];
    int t = threadIdx.x;
    float acc = 0.f;
    for (int k = 0; k < B / 256; ++k) acc += rowpart[t + k * 256];
    red[t] = acc;
    __syncthreads();
    for (int g = 128; g > 0; g >>= 1) {
        if (t < g) red[t] += red[t + g];
        __syncthreads();
    }
    if (t == 0) out[0] = red[0] / (float)B;
}

extern "C" void kernel_launch(void* const* d_in, const int* in_sizes, int n_in,
                              void* d_out, int out_size, void* d_ws, size_t ws_size,
                              hipStream_t stream) {
    const float* E      = (const float*)d_in[0];
    const int*   labels = (const int*)d_in[1];
    float*       out    = (float*)d_out;

    const size_t szE8   = (size_t)B * D;              // 8 MB
    const size_t szPart = (size_t)B * NRB * 4;        // 2 MB
    const size_t need   = szE8 + szPart + 4 * B + 4 * B + 4 * NCLS * MAXM
                        + 4 * NCLS + 4 * NCLS * 16 + 512;

    if (ws_size >= need) {
        char* ws = (char*)d_ws;
        unsigned char* E8 = (unsigned char*)ws;  ws += szE8;
        float* part    = (float*)ws;   ws += szPart;
        float* base    = (float*)ws;   ws += 4 * B;
        float* rowpart = (float*)ws;   ws += 4 * B;   (void)rowpart;
        int*   members = (int*)ws;     ws += 4 * NCLS * MAXM;
        int*   cnt     = (int*)ws;     ws += 4 * NCLS;
        float* part2   = (float*)ws;

        convert_classlist_kernel<<<NCONV + NCLS, 256, 0, stream>>>(E, E8, labels, members, cnt);
        lse_sym_kernel<<<NTRI, 256, 0, stream>>>(E8, labels, part);
        combine_kernel<<<B / 256, 256, 0, stream>>>(part, base);
        numer_mfma_kernel<<<dim3(NCLS, 4, 4), 256, 0, stream>>>(E8, base, members, cnt, part2);
        final2_kernel<<<1, 256, 0, stream>>>(part2, cnt, out);
    } else {
        char* ws = (char*)d_ws;
        float2* part   = (float2*)ws;  ws += sizeof(float2) * B * SPLITS;
        float* base    = (float*)ws;   ws += 4 * B;
        float* rowpart = (float*)ws;   ws += 4 * B;
        int*   members = (int*)ws;     ws += 4 * NCLS * MAXM;
        int*   cnt     = (int*)ws;

        lse_f32_kernel<<<dim3(B / BR, SPLITS), 256, 0, stream>>>(E, labels, part);
        combine_f32_kernel<<<B / 256, 256, 0, stream>>>(part, base);
        class_list_kernel<<<NCLS, 256, 0, stream>>>(labels, members, cnt);
        numer_kernel<<<B, 256, 0, stream>>>(E, labels, base, members, cnt, rowpart);
        final_kernel<<<1, 256, 0, stream>>>(rowpart, out);
    }
}